// Round 8
// baseline (6032.855 us; speedup 1.0000x reference)
//
#include <hip/hip_runtime.h>
#include <stdint.h>

#define TT 2048
#define BB 64
#define HH 256

// ws float-word layout
#define WIHT_OFF 0          // W_ih^T : 256 tokens x 1024 gate-rows
#define BIAS_OFF 262144     // b_ih + b_hh : 1024
#define HBUF_OFF 263168     // packed h exchange: u64[2][64][256] = 65536 floats
#define XMAP_OFF 328704     // 256 u32: per-WG published XCC id (0x100 | id)
#define WS_TOT   328960

#define LOGITS   33554432   // 64*2048*256

// ---------------- K1: prep (transpose W_ih, fuse biases, zero exch+xmap) ------
__global__ __launch_bounds__(256, 1) void k_prep(const float* __restrict__ W_ih,
                                                 const float* __restrict__ b_ih,
                                                 const float* __restrict__ b_hh,
                                                 float* ws_f) {
    int idx = blockIdx.x * 256 + threadIdx.x;
    if (idx < 262144) {
        int v = idx >> 10, r = idx & 1023;
        ws_f[WIHT_OFF + idx] = W_ih[r * 256 + v];
    } else if (idx < 263168) {
        int r = idx - 262144;
        ws_f[idx] = b_ih[r] + b_hh[r];
    } else if (idx < WS_TOT) {
        ws_f[idx] = 0.0f;   // exchange slots (epoch=0,val=0) + xcc map = 0
    }
}

// fast activations (no ocml branches); __expf -> v_exp_f32
__device__ __forceinline__ float sigm_f(float x) { return 1.0f / (1.0f + __expf(-x)); }
__device__ __forceinline__ float tanh_f(float x) {
    float e = __expf(2.0f * x);
    return 1.0f - 2.0f / (e + 1.0f);   // +-inf-safe: -> 1 / -1
}

// fast-path poll read. THEORY (explains r4 hang + r2/r7 sticky demotes): the
// poll address was read 2 steps earlier (parity ping-pong), so the consumer's
// vL1 holds a STALE allocated line; an sc0 load is a scope hint, not an L1
// bypass, so the "fast" poll kept re-reading stale L1 until the guard tripped
// and every passing round actually ran the MALL path. Fix: invalidate vL1
// (buffer_inv sc0 = L1-scope inv, gfx940+) before the load -> the load misses
// L1 and is served by the shared same-XCD L2, where the producer's
// write-through store landed. ~300cy spin vs ~900cy MALL.
__device__ __forceinline__ unsigned long long ld_l2i(const unsigned long long* p) {
    unsigned long long v;
    asm volatile("buffer_inv sc0\n\t"
                 "s_waitcnt vmcnt(0)\n\t"
                 "global_load_dwordx2 %0, %1, off sc0\n\t"
                 "s_waitcnt vmcnt(0)"
                 : "=v"(v) : "v"(p) : "memory");
    return v;
}
// fast-path store: sc0 store writes through vL1 into the local XCD L2 (dirty).
__device__ __forceinline__ void st_l2(unsigned long long* p, unsigned long long v) {
    asm volatile("global_store_dwordx2 %0, %1, off sc0" :: "v"(p), "v"(v) : "memory");
}

// LDS-only pre-barrier drain (HW-proven rounds 3/6/7). NO vmcnt: exchange
// stores are epoch-validated by their consumers, x_proj gathers land in
// private VGPRs, history stores have no in-kernel consumer.
__device__ __forceinline__ void bar_lds() {
    asm volatile("s_waitcnt lgkmcnt(0)" ::: "memory");
    __builtin_amdgcn_sched_barrier(0);
    __builtin_amdgcn_s_barrier();
    __builtin_amdgcn_sched_barrier(0);
}

// ---------------- K2: persistent LSTM recurrence ------------------------------
// ROUND-7 STRUCTURE VERBATIM (best measured: 5235 us) with exactly ONE change:
// the fast-path poll invalidates vL1 before loading (ld_l2i), so it can
// actually see the producer's L2-resident line instead of its own stale L1
// copy. Dual sc0+agent store and the sticky per-thread demote to the proven
// agent/MALL path are retained bit-identical -> a wrong theory degrades to
// round-7 behavior, never a hang.
__global__ __launch_bounds__(256, 1) void k_lstm(const int* __restrict__ x,
                                                 const float* __restrict__ W_hh,
                                                 const float* __restrict__ wsro,
                                                 unsigned long long* __restrict__ hbuf,
                                                 unsigned* __restrict__ xmap,
                                                 float* __restrict__ out) {
    const int tid = threadIdx.x;
    const int bid = blockIdx.x;
    const int xcd  = bid & 7;
    const int slot = bid >> 3;
    const int b = xcd + 8 * (slot >> 2);
    const int q = slot & 3;
    const int u  = tid & 63;
    const int w  = tid >> 6;            // wave id = quarter it polls; gate id
    const int j  = q * 64 + u;
    const int r  = w * 256 + j;         // gate row in [0,1024)

    __shared__ alignas(16) float hin[2][192];   // remote quarters, rotated, dbuf
    __shared__ alignas(16) float hloc[4][64];   // PER-WAVE private copy of own h
    __shared__ float gbuf[2][256];              // gate exchange, dbuf
    __shared__ int xs[4];

    // ---- one-time: W_hh row r -> regs, column-rotated (own quarter last) ----
    float4 w4[64];
#pragma unroll
    for (int i = 0; i < 64; ++i) {
        int cb = (i < 48) ? ((q + 1 + (i >> 4)) & 3) : q;
        int wi = (i < 48) ? (i & 15) : (i - 48);
        w4[i] = *(const float4*)(W_hh + (size_t)r * 256 + cb * 64 + wi * 4);
    }
    const float bias_r = wsro[BIAS_OFF + r];
    const int* xrow = x + b * TT;
    const bool ownw = (w == q);
    const int rb = (w - q + 3) & 3;     // rotated hin slot for polled quarter

    // ---- one-time: XCC handshake (ground truth; failure -> slow mode) ----
    int myxcc = 0;
    asm volatile("s_getreg_b32 %0, hwreg(HW_REG_XCC_ID)" : "=s"(myxcc));
    if (tid == 0)
        __hip_atomic_store(&xmap[bid], 0x100u | (unsigned)myxcc,
                           __ATOMIC_RELAXED, __HIP_MEMORY_SCOPE_AGENT);
    if (tid < 4) {
        int pb = (b & 7) + 8 * ((b >> 3) * 4 + tid);
        unsigned v; int g = 0;
        do {
            v = __hip_atomic_load(&xmap[pb], __ATOMIC_RELAXED, __HIP_MEMORY_SCOPE_AGENT);
        } while (!(v & 0x100u) && ++g < (1 << 20));
        xs[tid] = (v & 0x100u) ? (int)(v & 0xffu) : -1 - tid;  // timeout -> mismatch
    }
    hloc[w][u] = 0.0f;                  // h(0) = 0, every wave's private copy
    float c_state = 0.0f;               // redundant per wave, identical values
    float hval = 0.0f;
    __syncthreads();                    // one-time init barrier (full drain ok)
    bool fastm = (xs[0] == xs[1]) & (xs[1] == xs[2]) & (xs[2] == xs[3]);

    const float4* hl4 = (const float4*)hloc[w];

    // prefetch x_proj for t=0 (coalesced: 256B per wave)
    float xw_cur = wsro[WIHT_OFF + xrow[0] * 1024 + r] + bias_r;

    for (int t = 0; t < TT; ++t) {
        const int p = t & 1;
        // issue next step's gather NOW — a full step of latency cover
        const int tn = (t + 1 < TT) ? t + 1 : t;
        const float xw_next_raw = wsro[WIHT_OFF + xrow[tn] * 1024 + r];

        // own-quarter partial dot from the private hloc copy (same-wave RAW,
        // no barrier needed) — hides under the exchange latency
        float a0 = 0.f, a1 = 0.f, a2 = 0.f, a3 = 0.f;
#pragma unroll
        for (int i = 0; i < 16; ++i) {
            float4 hh = hl4[i];
            a0 += w4[48 + i].x * hh.x;
            a1 += w4[48 + i].y * hh.y;
            a2 += w4[48 + i].z * hh.z;
            a3 += w4[48 + i].w * hh.w;
        }

        // poll remote quarter (packed epoch|value), write rotated slot
        if (!ownw) {
            const unsigned long long* src = hbuf + (size_t)p * (BB * HH) + b * HH + tid;
            const unsigned ut = (unsigned)t;
            unsigned long long v = 0;
            if (fastm) {                 // L1-inv + shared-L2 poll, guarded
                int g = 0;
                do { v = ld_l2i(src); } while ((unsigned)(v >> 32) != ut && ++g < 6000);
                if ((unsigned)(v >> 32) != ut) fastm = false;  // sticky fallback
            }
            if (!fastm) {                // proven device-scope path
                int g = 0;
                do {
                    v = __hip_atomic_load(src, __ATOMIC_RELAXED, __HIP_MEMORY_SCOPE_AGENT);
                } while ((unsigned)(v >> 32) != ut && ++g < (1 << 21));
            }
            hin[p][rb * 64 + u] = __uint_as_float((unsigned)v);
        }
        bar_lds();                       // bar1: hin[p] ready (lgkm-only drain)

        // remaining 3 quarters, branch-free (rotation did the index mapping)
        const float4* hn4 = (const float4*)hin[p];
#pragma unroll
        for (int i = 0; i < 48; ++i) {
            float4 hh = hn4[i];
            a0 += w4[i].x * hh.x;
            a1 += w4[i].y * hh.y;
            a2 += w4[i].z * hh.z;
            a3 += w4[i].w * hh.w;
        }
        float gate = xw_cur + ((a0 + a1) + (a2 + a3));
        float act = (w == 2) ? tanh_f(gate) : sigm_f(gate);  // wave-uniform
        gbuf[p][tid] = act;
        bar_lds();                       // bar2: gbuf[p] ready (lgkm-only drain)

        // gate combine: redundant on all 4 waves (stride-1, conflict-free)
        float ig = gbuf[p][u],       fg = gbuf[p][64 + u];
        float gg = gbuf[p][128 + u], og = gbuf[p][192 + u];
        c_state = fg * c_state + ig * gg;
        hval = og * tanh_f(c_state);

        if (ownw) {                      // the non-polling wave produces
            unsigned long long pv =
                ((unsigned long long)(unsigned)(t + 1) << 32) |
                (unsigned long long)__float_as_uint(hval);
            unsigned long long* dst =
                hbuf + (size_t)((t + 1) & 1) * (BB * HH) + b * HH + j;
            if (fastm) st_l2(dst, pv);   // critical-path L2-resident store
            __hip_atomic_store(dst, pv, __ATOMIC_RELAXED, __HIP_MEMORY_SCOPE_AGENT);
            out[((size_t)(b * TT + t) << 8) + j] = hval;     // h history
        }
        hloc[w][u] = hval;               // private copy for next step's A
        xw_cur = xw_next_raw + bias_r;
    }

    if (ownw) {
        out[LOGITS + b * HH + j] = hval;                     // h_n
        out[LOGITS + BB * HH + b * HH + j] = c_state;        // c_n
    }
}

// ---------------- K3: FC epilogue, in-place over the logits region ------------
__global__ __launch_bounds__(256, 1) void k_fc(const float* __restrict__ fc_W,
                                               const float* __restrict__ fc_b,
                                               float* out) {
    __shared__ alignas(16) float ht[64][256];
    const int tid = threadIdx.x;
    const size_t base = (size_t)blockIdx.x * 64;
    for (int i = 0; i < 64; ++i)
        ht[i][tid] = out[(base + i) * 256 + tid];

    float4 w4[64];
    const float4* wr = (const float4*)(fc_W + (size_t)tid * 256);
#pragma unroll
    for (int k = 0; k < 64; ++k) w4[k] = wr[k];
    const float bias = fc_b[tid];
    __syncthreads();

    for (int m = 0; m < 64; ++m) {
        const float4* hv = (const float4*)ht[m];
        float a0 = 0.f, a1 = 0.f, a2 = 0.f, a3 = 0.f;
#pragma unroll
        for (int k = 0; k < 64; ++k) {
            float4 hh = hv[k];
            a0 += w4[k].x * hh.x;
            a1 += w4[k].y * hh.y;
            a2 += w4[k].z * hh.z;
            a3 += w4[k].w * hh.w;
        }
        out[(base + m) * 256 + tid] = bias + ((a0 + a1) + (a2 + a3));
    }
}

// ---------------- launch ------------------------------------------------------
extern "C" void kernel_launch(void* const* d_in, const int* in_sizes, int n_in,
                              void* d_out, int out_size, void* d_ws, size_t ws_size,
                              hipStream_t stream) {
    const int*   x    = (const int*)d_in[0];
    const float* W_ih = (const float*)d_in[1];
    const float* W_hh = (const float*)d_in[2];
    const float* b_ih = (const float*)d_in[3];
    const float* b_hh = (const float*)d_in[4];
    const float* fc_W = (const float*)d_in[5];
    const float* fc_b = (const float*)d_in[6];
    float* out  = (float*)d_out;
    float* ws_f = (float*)d_ws;
    unsigned long long* hbuf = (unsigned long long*)(ws_f + HBUF_OFF);
    unsigned* xmap = (unsigned*)(ws_f + XMAP_OFF);

    k_prep<<<(WS_TOT + 255) / 256, 256, 0, stream>>>(W_ih, b_ih, b_hh, ws_f);
    k_lstm<<<256, 256, 0, stream>>>(x, W_hh, ws_f, hbuf, xmap, out);
    k_fc<<<2048, 256, 0, stream>>>(fc_W, fc_b, out);
}